// Round 14
// baseline (211.278 us; speedup 1.0000x reference)
//
#include <hip/hip_runtime.h>

typedef short bf16x8 __attribute__((ext_vector_type(8)));
typedef float f32x4 __attribute__((ext_vector_type(4)));
typedef float f32x16 __attribute__((ext_vector_type(16)));

typedef const __attribute__((address_space(1))) void* gptr_t;
typedef __attribute__((address_space(3))) void* sptr_t;

#define Z16 {0.f,0.f,0.f,0.f,0.f,0.f,0.f,0.f,0.f,0.f,0.f,0.f,0.f,0.f,0.f,0.f}

__device__ __forceinline__ void glds16(const void* g, void* s) {
  __builtin_amdgcn_global_load_lds((gptr_t)g, (sptr_t)s, 16, 0, 0);
}

__device__ __forceinline__ unsigned short f2bf(float x) {
  unsigned u = __float_as_uint(x);
  u = u + 0x7fffu + ((u >> 16) & 1u);
  return (unsigned short)(u >> 16);
}

__device__ __forceinline__ unsigned packbf(float lo, float hi) {
  return (unsigned)f2bf(lo) | (((unsigned)f2bf(hi)) << 16);
}

// ------- fused prep: f32->bf16 convert (X,KY,VY,Wo) + Wq/Wk/Wv transpose --
// blocks [0,2048): convert; blocks [2048,2816): wtrans (idx = bid-2048).
__global__ __launch_bounds__(256) void prep(const float* __restrict__ X,
                                            const float* __restrict__ KY,
                                            const float* __restrict__ VY,
                                            const float* __restrict__ Wo,
                                            const float* __restrict__ Wq,
                                            const float* __restrict__ Wk,
                                            const float* __restrict__ Wv,
                                            unsigned short* __restrict__ XB,
                                            unsigned short* __restrict__ WOB,
                                            unsigned short* __restrict__ WT) {
  __shared__ float tile[64][65];
  if (blockIdx.x < 2048) {
    int stride = 2048 * 256;
    for (int i = blockIdx.x * 256 + threadIdx.x; i < 6553600; i += stride) {
      const float* in; unsigned short* out; int k;
      if (i < 2097152)      { in = X;  out = XB;            k = i; }
      else if (i < 4194304) { in = KY; out = XB + 8388608;  k = i - 2097152; }
      else if (i < 6291456) { in = VY; out = XB + 16777216; k = i - 4194304; }
      else                  { in = Wo; out = WOB;           k = i - 6291456; }
      float4 v = ((const float4*)in)[k];
      uint2 r;
      r.x = packbf(v.x, v.y);
      r.y = packbf(v.z, v.w);
      ((uint2*)out)[k] = r;
    }
    return;
  }
  int idx = blockIdx.x - 2048;            // 0..767
  int bx = idx & 15, by = idx >> 4;       // bx: d0/64, by: m*16+h
  int m = by >> 4, h = by & 15, d0 = bx * 64;
  const float* src = (m == 0 ? Wq : (m == 1 ? Wk : Wv)) + (size_t)h * 65536;
  int c = (threadIdx.x & 15) * 4, r0 = threadIdx.x >> 4;
#pragma unroll
  for (int rr = 0; rr < 4; ++rr) {
    int dr = rr * 16 + r0;
    float4 v = *(const float4*)(src + (size_t)(d0 + dr) * 64 + c);
    tile[dr][c + 0] = v.x; tile[dr][c + 1] = v.y;
    tile[dr][c + 2] = v.z; tile[dr][c + 3] = v.w;
  }
  __syncthreads();
#pragma unroll
  for (int rr = 0; rr < 4; ++rr) {
    int kr = rr * 16 + r0;
    uint2 pk;
    pk.x = packbf(tile[c + 0][kr], tile[c + 1][kr]);
    pk.y = packbf(tile[c + 2][kr], tile[c + 3][kr]);
    *(uint2*)(WT + ((size_t)(m * 1024 + h * 64 + kr)) * 1024 + d0 + c) = pk;
  }
}

// --------- QKV GEMM: 128x128 tile, dbuf 64KB, XCD m-slab swizzle ----------
__global__ __launch_bounds__(256) void gemm_qkv(const unsigned short* __restrict__ Ab,
                                                const unsigned short* __restrict__ Bb,
                                                const float* __restrict__ bi0,
                                                const float* __restrict__ bi1,
                                                const float* __restrict__ bi2,
                                                unsigned short* __restrict__ outp) {
  const int K = 1024;
  int z = blockIdx.z;
  const unsigned short* A = Ab + (size_t)z * 8192 * 1024;
  const unsigned short* BT = Bb + (size_t)z * 1024 * 1024;
  const float* bias = z == 0 ? bi0 : (z == 1 ? bi1 : bi2);
  int lin = blockIdx.y * 64 + blockIdx.x;           // 0..511
  int mt = (lin & 7) * 8 + ((lin >> 3) & 7);        // m-slab per XCD
  int nt = lin >> 6;                                // 0..7
  int m0 = mt * 128, n0 = nt * 128;
  __shared__ __align__(16) char lds[65536];  // 2 x (A 16KB + B 16KB)
  int tid = threadIdx.x, w = tid >> 6, l = tid & 63, ml = l & 15, hi = l >> 4;
  int wr = (w >> 1) * 64, wc = (w & 1) * 64;
  int srow = l >> 3;
  int kphys = (l & 7) << 4;
  f32x4 acc[4][4] = {};
#pragma unroll
  for (int i = 0; i < 4; ++i) {
    int c = w * 4 + i;
    int row = c * 8 + srow;
    int klog = kphys ^ ((row & 7) << 4);
    glds16((const char*)(A + (size_t)(m0 + row) * K) + klog, lds + c * 1024);
    glds16((const char*)(BT + (size_t)(n0 + row) * K) + klog, lds + 16384 + c * 1024);
  }
  __syncthreads();
  int cur = 0;
  for (int kt16 = 0; kt16 < 16; ++kt16) {
    if (kt16 + 1 < 16) {
      char* nb = lds + (cur ^ 1) * 32768;
      int kt = (kt16 + 1) * 64;
#pragma unroll
      for (int i = 0; i < 4; ++i) {
        int c = w * 4 + i;
        int row = c * 8 + srow;
        int klog = kphys ^ ((row & 7) << 4);
        glds16((const char*)(A + (size_t)(m0 + row) * K + kt) + klog, nb + c * 1024);
        glds16((const char*)(BT + (size_t)(n0 + row) * K + kt) + klog, nb + 16384 + c * 1024);
      }
    }
    char* As = lds + cur * 32768;
    char* Bs = As + 16384;
#pragma unroll
    for (int ks = 0; ks < 2; ++ks) {
      bf16x8 af[4], bfr[4];
#pragma unroll
      for (int mi = 0; mi < 4; ++mi) {
        int row = wr + mi * 16 + ml;
        af[mi] = *(const bf16x8*)(As + row * 128 + ((ks * 64 + (hi << 4)) ^ ((row & 7) << 4)));
      }
#pragma unroll
      for (int ni = 0; ni < 4; ++ni) {
        int row = wc + ni * 16 + ml;
        bfr[ni] = *(const bf16x8*)(Bs + row * 128 + ((ks * 64 + (hi << 4)) ^ ((row & 7) << 4)));
      }
      __builtin_amdgcn_s_setprio(1);
#pragma unroll
      for (int mi = 0; mi < 4; ++mi)
#pragma unroll
        for (int ni = 0; ni < 4; ++ni)
          acc[mi][ni] = __builtin_amdgcn_mfma_f32_16x16x32_bf16(af[mi], bfr[ni], acc[mi][ni], 0, 0, 0);
      __builtin_amdgcn_s_setprio(0);
    }
    __syncthreads();
    cur ^= 1;
  }
#pragma unroll
  for (int mi = 0; mi < 4; ++mi) {
#pragma unroll
    for (int ni = 0; ni < 4; ++ni) {
      int col = wc + ni * 16 + ml;  // local 0..127
      float bv = bias[n0 + col];
#pragma unroll
      for (int r = 0; r < 4; ++r) {
        int row = wr + mi * 16 + (hi << 2) + r;  // local 0..127
        float v = acc[mi][ni][r] + bv;
        float pv = __shfl_xor(v, 1);
        unsigned pk = (ml & 1) ? packbf(pv, v) : packbf(v, pv);
        *(unsigned*)(lds + row * 256 + (((col * 2) & ~3) ^ ((row & 7) << 4))) = pk;
      }
    }
  }
  __syncthreads();
  unsigned short* ob = outp + (size_t)z * 8388608;
  if (z != 2) {
    int rr = tid >> 1, hh = tid & 1;
    int t = (m0 + rr) >> 3, b = (m0 + rr) & 7;
    int hg = (n0 >> 6) + hh;
    unsigned short* dst = ob + (size_t)(b * 16 + hg) * 65536 + (size_t)t * 64;
#pragma unroll
    for (int j = 0; j < 8; ++j) {
      uint4 d = *(uint4*)(lds + rr * 256 + ((hh * 128 + j * 16) ^ ((rr & 7) << 4)));
      *(uint4*)(dst + j * 8) = d;
    }
  } else {
    int t0 = m0 >> 3;
#pragma unroll
    for (int q = 0; q < 4; ++q) {
      int run = q * 256 + tid;
      int k = run & 63;
      int bh2 = run >> 6;           // 0..15
      int b = bh2 >> 1, hh = bh2 & 1;
      int colb = (hh * 64 + k) * 2;
      union { unsigned short u[16]; uint4 v[2]; } tmp;
#pragma unroll
      for (int tp = 0; tp < 16; ++tp) {
        int rowt = tp * 8 + b;
        tmp.u[tp] = *(unsigned short*)(lds + rowt * 256 + (colb ^ ((b & 7) << 4)));
      }
      int hg = (n0 >> 6) + hh;
      unsigned short* dst = ob + (size_t)(b * 16 + hg) * 65536 + (size_t)k * 1024 + t0;
      *(uint4*)dst = tmp.v[0];
      *(uint4*)(dst + 8) = tmp.v[1];
    }
  }
}

// --------- Output GEMM: 128x128 tile, dbuf 64KB, XCD swizzle, f32 out -----
__global__ __launch_bounds__(256) void gemm_out(const unsigned short* __restrict__ A,
                                                const unsigned short* __restrict__ BT,
                                                const float* __restrict__ bias,
                                                float* __restrict__ outp) {
  const int K = 1024;
  int lin = blockIdx.y * 64 + blockIdx.x;           // 0..511
  int mt = (lin & 7) * 8 + ((lin >> 3) & 7);
  int nt = lin >> 6;
  int m0 = mt * 128, n0 = nt * 128;
  __shared__ __align__(16) char lds[65536];
  int tid = threadIdx.x, w = tid >> 6, l = tid & 63, ml = l & 15, hi = l >> 4;
  int wr = (w >> 1) * 64, wc = (w & 1) * 64;
  int srow = l >> 3;
  int kphys = (l & 7) << 4;
  f32x4 acc[4][4] = {};
#pragma unroll
  for (int i = 0; i < 4; ++i) {
    int c = w * 4 + i;
    int row = c * 8 + srow;
    int klog = kphys ^ ((row & 7) << 4);
    glds16((const char*)(A + (size_t)(m0 + row) * K) + klog, lds + c * 1024);
    glds16((const char*)(BT + (size_t)(n0 + row) * K) + klog, lds + 16384 + c * 1024);
  }
  __syncthreads();
  int cur = 0;
  for (int kt16 = 0; kt16 < 16; ++kt16) {
    if (kt16 + 1 < 16) {
      char* nb = lds + (cur ^ 1) * 32768;
      int kt = (kt16 + 1) * 64;
#pragma unroll
      for (int i = 0; i < 4; ++i) {
        int c = w * 4 + i;
        int row = c * 8 + srow;
        int klog = kphys ^ ((row & 7) << 4);
        glds16((const char*)(A + (size_t)(m0 + row) * K + kt) + klog, nb + c * 1024);
        glds16((const char*)(BT + (size_t)(n0 + row) * K + kt) + klog, nb + 16384 + c * 1024);
      }
    }
    char* As = lds + cur * 32768;
    char* Bs = As + 16384;
#pragma unroll
    for (int ks = 0; ks < 2; ++ks) {
      bf16x8 af[4], bfr[4];
#pragma unroll
      for (int mi = 0; mi < 4; ++mi) {
        int row = wr + mi * 16 + ml;
        af[mi] = *(const bf16x8*)(As + row * 128 + ((ks * 64 + (hi << 4)) ^ ((row & 7) << 4)));
      }
#pragma unroll
      for (int ni = 0; ni < 4; ++ni) {
        int row = wc + ni * 16 + ml;
        bfr[ni] = *(const bf16x8*)(Bs + row * 128 + ((ks * 64 + (hi << 4)) ^ ((row & 7) << 4)));
      }
      __builtin_amdgcn_s_setprio(1);
#pragma unroll
      for (int mi = 0; mi < 4; ++mi)
#pragma unroll
        for (int ni = 0; ni < 4; ++ni)
          acc[mi][ni] = __builtin_amdgcn_mfma_f32_16x16x32_bf16(af[mi], bfr[ni], acc[mi][ni], 0, 0, 0);
      __builtin_amdgcn_s_setprio(0);
    }
    __syncthreads();
    cur ^= 1;
  }
#pragma unroll
  for (int mi = 0; mi < 4; ++mi) {
#pragma unroll
    for (int ni = 0; ni < 4; ++ni) {
      int col = n0 + wc + ni * 16 + ml;
      float bv = bias[col];
#pragma unroll
      for (int r = 0; r < 4; ++r) {
        int row = m0 + wr + mi * 16 + (hi << 2) + r;
        outp[(size_t)row * 1024 + col] = acc[mi][ni][r] + bv;
      }
    }
  }
}

// -------- causal flash attention: barrier-free, direct-L2 K/V reads -------
// 512 blocks x 8 waves; balanced stripes; per-wave loop st=0..stripe only.
// K/V per XCD working set = 2 MB (L2-fit) via bh co-location -> no staging.
__global__ __launch_bounds__(512, 4) void attn_k(const unsigned short* __restrict__ Qp,
                                                 const unsigned short* __restrict__ Kp,
                                                 const unsigned short* __restrict__ VTp,
                                                 unsigned short* __restrict__ Op,
                                                 const int* __restrict__ maskp) {
  int lin = blockIdx.x;
  int xcd = lin & 7, idx = lin >> 3;
  int bh = xcd + 8 * (idx >> 2);     // 4 blocks of each bh share an XCD
  int j = idx & 3;
  const size_t base = (size_t)bh * 65536;
  int tid = threadIdx.x, w = tid >> 6, l = tid & 63;
  int ml5 = l & 31, hi1 = l >> 5;
  int half = w & 1, pi = w >> 1;
  int stripe = (pi == 0) ? j : (pi == 1) ? (15 - j) : (pi == 2) ? (7 - j) : (8 + j);
  int tw0 = stripe * 64 + half * 32;
  int t_glob = tw0 + ml5;
  int msk = *maskp;
  const float CE = 0.18033688011112042f;  // 0.125 * log2(e)
  bf16x8 bq[4];
#pragma unroll
  for (int kd = 0; kd < 4; ++kd)
    bq[kd] = *(const bf16x8*)(Qp + base + (size_t)t_glob * 64 + kd * 16 + hi1 * 8);
  f32x16 o0 = Z16, o1 = Z16;
  float m_run = -3e38f, l_run = 0.f;
  int lim = msk ? stripe : 15;
  const unsigned short* krow = Kp + base + (size_t)ml5 * 64 + hi1 * 8;   // +kd*16
  const unsigned short* vrow = VTp + base + (size_t)ml5 * 1024 + hi1 * 8; // +kb*16
  for (int st = 0; st <= lim; ++st) {
    // ---- S^T = K·Q^T (K fragments direct from L2) ----
    f32x16 s0 = Z16, s1 = Z16;
    const unsigned short* ka = krow + st * 4096;
    __builtin_amdgcn_s_setprio(1);
#pragma unroll
    for (int kd = 0; kd < 4; ++kd) {
      bf16x8 a0 = *(const bf16x8*)(ka + kd * 16);
      bf16x8 a1 = *(const bf16x8*)(ka + 2048 + kd * 16);
      s0 = __builtin_amdgcn_mfma_f32_32x32x16_bf16(a0, bq[kd], s0, 0, 0, 0);
      s1 = __builtin_amdgcn_mfma_f32_32x32x16_bf16(a1, bq[kd], s1, 0, 0, 0);
    }
    __builtin_amdgcn_s_setprio(0);
    if (msk && st == stripe) {
#pragma unroll
      for (int r = 0; r < 16; ++r) {
        int sl = st * 64 + (r & 3) + 8 * (r >> 2) + 4 * hi1;
        if (sl > t_glob) s0[r] = -1e30f;
        if (sl + 32 > t_glob) s1[r] = -1e30f;
      }
    }
    // ---- in-register online softmax with defer-max (T13) ----
    float t8[8];
#pragma unroll
    for (int r = 0; r < 8; ++r)
      t8[r] = fmaxf(fmaxf(s0[r], s0[r + 8]), fmaxf(s1[r], s1[r + 8]));
    float tm = fmaxf(fmaxf(fmaxf(t8[0], t8[1]), fmaxf(t8[2], t8[3])),
                     fmaxf(fmaxf(t8[4], t8[5]), fmaxf(t8[6], t8[7])));
    tm = fmaxf(tm, __shfl_xor(tm, 32));
    if (!__all(tm <= m_run + 8.0f)) {
      float m_new = fmaxf(m_run, tm);
      float sc2 = exp2f((m_run - m_new) * CE);
      l_run *= sc2;
#pragma unroll
      for (int r = 0; r < 16; ++r) { o0[r] *= sc2; o1[r] *= sc2; }
      m_run = m_new;
    }
    float mC = m_run * CE;
#pragma unroll
    for (int r = 0; r < 16; ++r) {
      s0[r] = exp2f(fmaf(s0[r], CE, -mC));
      s1[r] = exp2f(fmaf(s1[r], CE, -mC));
    }
    float a8[8];
#pragma unroll
    for (int r = 0; r < 8; ++r)
      a8[r] = (s0[r] + s0[r + 8]) + (s1[r] + s1[r + 8]);
    float ps = ((a8[0] + a8[1]) + (a8[2] + a8[3])) + ((a8[4] + a8[5]) + (a8[6] + a8[7]));
    ps += __shfl_xor(ps, 32);
    l_run += ps;
    // ---- pack P to bf16, redistribute across the 32-lane halves ----
    unsigned cc0[4][2], cc1[4][2];
#pragma unroll
    for (int q = 0; q < 4; ++q) {
      cc0[q][0] = packbf(s0[4 * q + 0], s0[4 * q + 1]);
      cc0[q][1] = packbf(s0[4 * q + 2], s0[4 * q + 3]);
      cc1[q][0] = packbf(s1[4 * q + 0], s1[4 * q + 1]);
      cc1[q][1] = packbf(s1[4 * q + 2], s1[4 * q + 3]);
    }
#define CCa(a, p) ((a) < 4 ? cc0[(a) & 3][p] : cc1[(a) & 3][p])
    union U4 { unsigned u[4]; bf16x8 v; };
    bf16x8 pb[4];
#pragma unroll
    for (int kb = 0; kb < 4; ++kb) {
      U4 t;
#pragma unroll
      for (int p = 0; p < 2; ++p) {
        unsigned x = CCa(2 * kb, p), y = CCa(2 * kb + 1, p);
        unsigned v = hi1 ? x : y;
        unsigned wv = hi1 ? y : x;
        unsigned vs = __shfl_xor(v, 32);
        t.u[p]     = hi1 ? vs : wv;
        t.u[2 + p] = hi1 ? wv : vs;
      }
      pb[kb] = t.v;
    }
#undef CCa
    // ---- O^T += V^T · P^T (V fragments direct from L2) ----
    const unsigned short* va = vrow + st * 64;
    __builtin_amdgcn_s_setprio(1);
#pragma unroll
    for (int kb = 0; kb < 4; ++kb) {
      bf16x8 v0 = *(const bf16x8*)(va + kb * 16);
      bf16x8 v1 = *(const bf16x8*)(va + 32768 + kb * 16);
      o0 = __builtin_amdgcn_mfma_f32_32x32x16_bf16(v0, pb[kb], o0, 0, 0, 0);
      o1 = __builtin_amdgcn_mfma_f32_32x32x16_bf16(v1, pb[kb], o1, 0, 0, 0);
    }
    __builtin_amdgcn_s_setprio(0);
  }
  // ---- epilogue: O /= l, store bf16 row t_glob ----
  float rl = 1.0f / l_run;
  int b = bh >> 4, h = bh & 15;
  unsigned short* orow = Op + (size_t)(t_glob * 8 + b) * 1024 + h * 64;
#pragma unroll
  for (int q2 = 0; q2 < 4; ++q2) {
    uint2 pk0, pk1;
    pk0.x = packbf(o0[4 * q2 + 0] * rl, o0[4 * q2 + 1] * rl);
    pk0.y = packbf(o0[4 * q2 + 2] * rl, o0[4 * q2 + 3] * rl);
    *(uint2*)(orow + 4 * hi1 + 8 * q2) = pk0;
    pk1.x = packbf(o1[4 * q2 + 0] * rl, o1[4 * q2 + 1] * rl);
    pk1.y = packbf(o1[4 * q2 + 2] * rl, o1[4 * q2 + 3] * rl);
    *(uint2*)(orow + 32 + 4 * hi1 + 8 * q2) = pk1;
  }
}

extern "C" void kernel_launch(void* const* d_in, const int* in_sizes, int n_in,
                              void* d_out, int out_size, void* d_ws, size_t ws_size,
                              hipStream_t stream) {
  const float* X  = (const float*)d_in[0];
  const float* KY = (const float*)d_in[1];
  const float* VY = (const float*)d_in[2];
  const float* Wq = (const float*)d_in[3];
  const float* bq = (const float*)d_in[4];
  const float* Wk = (const float*)d_in[5];
  const float* bk = (const float*)d_in[6];
  const float* Wv = (const float*)d_in[7];
  const float* bv = (const float*)d_in[8];
  const float* Wo = (const float*)d_in[9];
  const float* bo = (const float*)d_in[10];
  const int* mask = (const int*)d_in[11];
  char* ws = (char*)d_ws;
  unsigned short* XB  = (unsigned short*)(ws);                       // [3][8192][1024] bf16
  unsigned short* WT  = (unsigned short*)(ws + 48ll * 1024 * 1024);  // [3][1024][1024] bf16
  unsigned short* WOB = (unsigned short*)(ws + 54ll * 1024 * 1024);  // [1024][1024] bf16
  unsigned short* QP  = (unsigned short*)(ws + 56ll * 1024 * 1024);  // Q,K:[B,H,T,64]; V:[B,H,64,T]
  unsigned short* OP  = (unsigned short*)(ws + 104ll * 1024 * 1024); // [8192][1024] bf16

  prep<<<2816, 256, 0, stream>>>(X, KY, VY, Wo, Wq, Wk, Wv, XB, WOB, WT);
  gemm_qkv<<<dim3(64, 8, 3), 256, 0, stream>>>(XB, WT, bq, bk, bv, QP);
  attn_k<<<512, 512, 0, stream>>>(QP, QP + 8388608, QP + 16777216, OP, mask);
  gemm_out<<<dim3(64, 8, 1), 256, 0, stream>>>(OP, WOB, bo, (float*)d_out);
}

// Round 15
// 185.310 us; speedup vs baseline: 1.1401x; 1.1401x over previous
//
#include <hip/hip_runtime.h>

typedef short bf16x8 __attribute__((ext_vector_type(8)));
typedef float f32x4 __attribute__((ext_vector_type(4)));
typedef float f32x16 __attribute__((ext_vector_type(16)));

typedef const __attribute__((address_space(1))) void* gptr_t;
typedef __attribute__((address_space(3))) void* sptr_t;

#define Z16 {0.f,0.f,0.f,0.f,0.f,0.f,0.f,0.f,0.f,0.f,0.f,0.f,0.f,0.f,0.f,0.f}
#define VMCNT(n) asm volatile("s_waitcnt vmcnt(" #n ")" ::: "memory")
#define LGKM0 asm volatile("s_waitcnt lgkmcnt(0)" ::: "memory")
#define SCHEDB __builtin_amdgcn_sched_barrier(0)
#define SBAR __builtin_amdgcn_s_barrier()

__device__ __forceinline__ void glds16(const void* g, void* s) {
  __builtin_amdgcn_global_load_lds((gptr_t)g, (sptr_t)s, 16, 0, 0);
}

__device__ __forceinline__ unsigned short f2bf(float x) {
  unsigned u = __float_as_uint(x);
  u = u + 0x7fffu + ((u >> 16) & 1u);
  return (unsigned short)(u >> 16);
}

__device__ __forceinline__ unsigned packbf(float lo, float hi) {
  return (unsigned)f2bf(lo) | (((unsigned)f2bf(hi)) << 16);
}

// ------- fused prep: f32->bf16 convert (X,KY,VY,Wo) + Wq/Wk/Wv transpose --
__global__ __launch_bounds__(256) void prep(const float* __restrict__ X,
                                            const float* __restrict__ KY,
                                            const float* __restrict__ VY,
                                            const float* __restrict__ Wo,
                                            const float* __restrict__ Wq,
                                            const float* __restrict__ Wk,
                                            const float* __restrict__ Wv,
                                            unsigned short* __restrict__ XB,
                                            unsigned short* __restrict__ WOB,
                                            unsigned short* __restrict__ WT) {
  __shared__ float tile[64][65];
  if (blockIdx.x < 2048) {
    int stride = 2048 * 256;
    for (int i = blockIdx.x * 256 + threadIdx.x; i < 6553600; i += stride) {
      const float* in; unsigned short* out; int k;
      if (i < 2097152)      { in = X;  out = XB;            k = i; }
      else if (i < 4194304) { in = KY; out = XB + 8388608;  k = i - 2097152; }
      else if (i < 6291456) { in = VY; out = XB + 16777216; k = i - 4194304; }
      else                  { in = Wo; out = WOB;           k = i - 6291456; }
      float4 v = ((const float4*)in)[k];
      uint2 r;
      r.x = packbf(v.x, v.y);
      r.y = packbf(v.z, v.w);
      ((uint2*)out)[k] = r;
    }
    return;
  }
  int idx = blockIdx.x - 2048;            // 0..767
  int bx = idx & 15, by = idx >> 4;       // bx: d0/64, by: m*16+h
  int m = by >> 4, h = by & 15, d0 = bx * 64;
  const float* src = (m == 0 ? Wq : (m == 1 ? Wk : Wv)) + (size_t)h * 65536;
  int c = (threadIdx.x & 15) * 4, r0 = threadIdx.x >> 4;
#pragma unroll
  for (int rr = 0; rr < 4; ++rr) {
    int dr = rr * 16 + r0;
    float4 v = *(const float4*)(src + (size_t)(d0 + dr) * 64 + c);
    tile[dr][c + 0] = v.x; tile[dr][c + 1] = v.y;
    tile[dr][c + 2] = v.z; tile[dr][c + 3] = v.w;
  }
  __syncthreads();
#pragma unroll
  for (int rr = 0; rr < 4; ++rr) {
    int kr = rr * 16 + r0;
    uint2 pk;
    pk.x = packbf(tile[c + 0][kr], tile[c + 1][kr]);
    pk.y = packbf(tile[c + 2][kr], tile[c + 3][kr]);
    *(uint2*)(WT + ((size_t)(m * 1024 + h * 64 + kr)) * 1024 + d0 + c) = pk;
  }
}

// --------- QKV GEMM: 128x128 tile, dbuf 64KB, XCD m-slab swizzle ----------
__global__ __launch_bounds__(256) void gemm_qkv(const unsigned short* __restrict__ Ab,
                                                const unsigned short* __restrict__ Bb,
                                                const float* __restrict__ bi0,
                                                const float* __restrict__ bi1,
                                                const float* __restrict__ bi2,
                                                unsigned short* __restrict__ outp) {
  const int K = 1024;
  int z = blockIdx.z;
  const unsigned short* A = Ab + (size_t)z * 8192 * 1024;
  const unsigned short* BT = Bb + (size_t)z * 1024 * 1024;
  const float* bias = z == 0 ? bi0 : (z == 1 ? bi1 : bi2);
  int lin = blockIdx.y * 64 + blockIdx.x;           // 0..511
  int mt = (lin & 7) * 8 + ((lin >> 3) & 7);        // m-slab per XCD
  int nt = lin >> 6;                                // 0..7
  int m0 = mt * 128, n0 = nt * 128;
  __shared__ __align__(16) char lds[65536];  // 2 x (A 16KB + B 16KB)
  int tid = threadIdx.x, w = tid >> 6, l = tid & 63, ml = l & 15, hi = l >> 4;
  int wr = (w >> 1) * 64, wc = (w & 1) * 64;
  int srow = l >> 3;
  int kphys = (l & 7) << 4;
  f32x4 acc[4][4] = {};
#pragma unroll
  for (int i = 0; i < 4; ++i) {
    int c = w * 4 + i;
    int row = c * 8 + srow;
    int klog = kphys ^ ((row & 7) << 4);
    glds16((const char*)(A + (size_t)(m0 + row) * K) + klog, lds + c * 1024);
    glds16((const char*)(BT + (size_t)(n0 + row) * K) + klog, lds + 16384 + c * 1024);
  }
  __syncthreads();
  int cur = 0;
  for (int kt16 = 0; kt16 < 16; ++kt16) {
    if (kt16 + 1 < 16) {
      char* nb = lds + (cur ^ 1) * 32768;
      int kt = (kt16 + 1) * 64;
#pragma unroll
      for (int i = 0; i < 4; ++i) {
        int c = w * 4 + i;
        int row = c * 8 + srow;
        int klog = kphys ^ ((row & 7) << 4);
        glds16((const char*)(A + (size_t)(m0 + row) * K + kt) + klog, nb + c * 1024);
        glds16((const char*)(BT + (size_t)(n0 + row) * K + kt) + klog, nb + 16384 + c * 1024);
      }
    }
    char* As = lds + cur * 32768;
    char* Bs = As + 16384;
#pragma unroll
    for (int ks = 0; ks < 2; ++ks) {
      bf16x8 af[4], bfr[4];
#pragma unroll
      for (int mi = 0; mi < 4; ++mi) {
        int row = wr + mi * 16 + ml;
        af[mi] = *(const bf16x8*)(As + row * 128 + ((ks * 64 + (hi << 4)) ^ ((row & 7) << 4)));
      }
#pragma unroll
      for (int ni = 0; ni < 4; ++ni) {
        int row = wc + ni * 16 + ml;
        bfr[ni] = *(const bf16x8*)(Bs + row * 128 + ((ks * 64 + (hi << 4)) ^ ((row & 7) << 4)));
      }
      __builtin_amdgcn_s_setprio(1);
#pragma unroll
      for (int mi = 0; mi < 4; ++mi)
#pragma unroll
        for (int ni = 0; ni < 4; ++ni)
          acc[mi][ni] = __builtin_amdgcn_mfma_f32_16x16x32_bf16(af[mi], bfr[ni], acc[mi][ni], 0, 0, 0);
      __builtin_amdgcn_s_setprio(0);
    }
    __syncthreads();
    cur ^= 1;
  }
#pragma unroll
  for (int mi = 0; mi < 4; ++mi) {
#pragma unroll
    for (int ni = 0; ni < 4; ++ni) {
      int col = wc + ni * 16 + ml;  // local 0..127
      float bv = bias[n0 + col];
#pragma unroll
      for (int r = 0; r < 4; ++r) {
        int row = wr + mi * 16 + (hi << 2) + r;  // local 0..127
        float v = acc[mi][ni][r] + bv;
        float pv = __shfl_xor(v, 1);
        unsigned pk = (ml & 1) ? packbf(pv, v) : packbf(v, pv);
        *(unsigned*)(lds + row * 256 + (((col * 2) & ~3) ^ ((row & 7) << 4))) = pk;
      }
    }
  }
  __syncthreads();
  unsigned short* ob = outp + (size_t)z * 8388608;
  if (z != 2) {
    int rr = tid >> 1, hh = tid & 1;
    int t = (m0 + rr) >> 3, b = (m0 + rr) & 7;
    int hg = (n0 >> 6) + hh;
    unsigned short* dst = ob + (size_t)(b * 16 + hg) * 65536 + (size_t)t * 64;
#pragma unroll
    for (int j = 0; j < 8; ++j) {
      uint4 d = *(uint4*)(lds + rr * 256 + ((hh * 128 + j * 16) ^ ((rr & 7) << 4)));
      *(uint4*)(dst + j * 8) = d;
    }
  } else {
    int t0 = m0 >> 3;
#pragma unroll
    for (int q = 0; q < 4; ++q) {
      int run = q * 256 + tid;
      int k = run & 63;
      int bh2 = run >> 6;           // 0..15
      int b = bh2 >> 1, hh = bh2 & 1;
      int colb = (hh * 64 + k) * 2;
      union { unsigned short u[16]; uint4 v[2]; } tmp;
#pragma unroll
      for (int tp = 0; tp < 16; ++tp) {
        int rowt = tp * 8 + b;
        tmp.u[tp] = *(unsigned short*)(lds + rowt * 256 + (colb ^ ((b & 7) << 4)));
      }
      int hg = (n0 >> 6) + hh;
      unsigned short* dst = ob + (size_t)(b * 16 + hg) * 65536 + (size_t)k * 1024 + t0;
      *(uint4*)dst = tmp.v[0];
      *(uint4*)(dst + 8) = tmp.v[1];
    }
  }
}

// --------- Output GEMM: 128x128 tile, dbuf 64KB, XCD swizzle, f32 out -----
__global__ __launch_bounds__(256) void gemm_out(const unsigned short* __restrict__ A,
                                                const unsigned short* __restrict__ BT,
                                                const float* __restrict__ bias,
                                                float* __restrict__ outp) {
  const int K = 1024;
  int lin = blockIdx.y * 64 + blockIdx.x;           // 0..511
  int mt = (lin & 7) * 8 + ((lin >> 3) & 7);
  int nt = lin >> 6;
  int m0 = mt * 128, n0 = nt * 128;
  __shared__ __align__(16) char lds[65536];
  int tid = threadIdx.x, w = tid >> 6, l = tid & 63, ml = l & 15, hi = l >> 4;
  int wr = (w >> 1) * 64, wc = (w & 1) * 64;
  int srow = l >> 3;
  int kphys = (l & 7) << 4;
  f32x4 acc[4][4] = {};
#pragma unroll
  for (int i = 0; i < 4; ++i) {
    int c = w * 4 + i;
    int row = c * 8 + srow;
    int klog = kphys ^ ((row & 7) << 4);
    glds16((const char*)(A + (size_t)(m0 + row) * K) + klog, lds + c * 1024);
    glds16((const char*)(BT + (size_t)(n0 + row) * K) + klog, lds + 16384 + c * 1024);
  }
  __syncthreads();
  int cur = 0;
  for (int kt16 = 0; kt16 < 16; ++kt16) {
    if (kt16 + 1 < 16) {
      char* nb = lds + (cur ^ 1) * 32768;
      int kt = (kt16 + 1) * 64;
#pragma unroll
      for (int i = 0; i < 4; ++i) {
        int c = w * 4 + i;
        int row = c * 8 + srow;
        int klog = kphys ^ ((row & 7) << 4);
        glds16((const char*)(A + (size_t)(m0 + row) * K + kt) + klog, nb + c * 1024);
        glds16((const char*)(BT + (size_t)(n0 + row) * K + kt) + klog, nb + 16384 + c * 1024);
      }
    }
    char* As = lds + cur * 32768;
    char* Bs = As + 16384;
#pragma unroll
    for (int ks = 0; ks < 2; ++ks) {
      bf16x8 af[4], bfr[4];
#pragma unroll
      for (int mi = 0; mi < 4; ++mi) {
        int row = wr + mi * 16 + ml;
        af[mi] = *(const bf16x8*)(As + row * 128 + ((ks * 64 + (hi << 4)) ^ ((row & 7) << 4)));
      }
#pragma unroll
      for (int ni = 0; ni < 4; ++ni) {
        int row = wc + ni * 16 + ml;
        bfr[ni] = *(const bf16x8*)(Bs + row * 128 + ((ks * 64 + (hi << 4)) ^ ((row & 7) << 4)));
      }
      __builtin_amdgcn_s_setprio(1);
#pragma unroll
      for (int mi = 0; mi < 4; ++mi)
#pragma unroll
        for (int ni = 0; ni < 4; ++ni)
          acc[mi][ni] = __builtin_amdgcn_mfma_f32_16x16x32_bf16(af[mi], bfr[ni], acc[mi][ni], 0, 0, 0);
      __builtin_amdgcn_s_setprio(0);
    }
    __syncthreads();
    cur ^= 1;
  }
#pragma unroll
  for (int mi = 0; mi < 4; ++mi) {
#pragma unroll
    for (int ni = 0; ni < 4; ++ni) {
      int col = n0 + wc + ni * 16 + ml;
      float bv = bias[col];
#pragma unroll
      for (int r = 0; r < 4; ++r) {
        int row = m0 + wr + mi * 16 + (hi << 2) + r;
        outp[(size_t)row * 1024 + col] = acc[mi][ni][r] + bv;
      }
    }
  }
}

// -------- causal flash attention: 2-wave blocks, uniform work -------------
// Block = (bh, stripe s). Wave w owns rows [64s+32w, +32); loop st=0..s.
// Wave 0 stages K tile, wave 1 stages V^T tile; dbuf 32KB, counted VMCNT(8).
__global__ __launch_bounds__(128, 2) void attn_k(const unsigned short* __restrict__ Qp,
                                                 const unsigned short* __restrict__ Kp,
                                                 const unsigned short* __restrict__ VTp,
                                                 unsigned short* __restrict__ Op,
                                                 const int* __restrict__ maskp) {
  int lin = blockIdx.x;
  int xcd = lin & 7, idx = lin >> 3;
  int bh = xcd + 8 * (idx & 15);       // all 16 stripes of a bh share an XCD
  int s = 15 - (idx >> 4);             // descending: long blocks first
  const size_t base = (size_t)bh * 65536;
  int tid = threadIdx.x, w = tid >> 6, l = tid & 63;
  int ml5 = l & 31, hi1 = l >> 5;
  int tw0 = s * 64 + w * 32;
  int t_glob = tw0 + ml5;
  __shared__ __align__(16) char lds[32768];  // 2 buffers x (K 8KB + V 8KB)
  int msk = *maskp;
  const float CE = 0.18033688011112042f;  // 0.125 * log2(e)
  bf16x8 bq[4];
#pragma unroll
  for (int kd = 0; kd < 4; ++kd)
    bq[kd] = *(const bf16x8*)(Qp + base + (size_t)t_glob * 64 + kd * 16 + hi1 * 8);
  f32x16 o0 = Z16, o1 = Z16;
  float m_run = -3e38f, l_run = 0.f;
  int lim = msk ? s : 15;
  int srow = l >> 3, kphys = (l & 7) << 4;
  int klog = kphys ^ (srow << 4);
  int swz = (ml5 & 7) << 4;
  // prologue: stage tile 0 into buffer 0 (wave0: K, wave1: V)
  if (w == 0) {
#pragma unroll
    for (int i = 0; i < 8; ++i) {
      int row = i * 8 + srow;
      glds16((const char*)(Kp + base + (size_t)row * 64) + klog, lds + i * 1024);
    }
  } else {
#pragma unroll
    for (int i = 0; i < 8; ++i) {
      int row = i * 8 + srow;
      glds16((const char*)(VTp + base + (size_t)row * 1024) + klog, lds + 8192 + i * 1024);
    }
  }
  int cur = 0;
  for (int st = 0; st <= lim; ++st) {
    if (st < lim) {  // prefetch next tile into the other buffer
      char* nb = lds + (cur ^ 1) * 16384;
      if (w == 0) {
#pragma unroll
        for (int i = 0; i < 8; ++i) {
          int row = i * 8 + srow;
          glds16((const char*)(Kp + base + (size_t)((st + 1) * 64 + row) * 64) + klog, nb + i * 1024);
        }
      } else {
#pragma unroll
        for (int i = 0; i < 8; ++i) {
          int row = i * 8 + srow;
          glds16((const char*)(VTp + base + (size_t)row * 1024 + (st + 1) * 64) + klog, nb + 8192 + i * 1024);
        }
      }
      VMCNT(8);
    } else {
      VMCNT(0);
    }
    SCHEDB; SBAR; SCHEDB;
    char* Ks = lds + cur * 16384;
    char* Vs = Ks + 8192;
    // ---- S^T = K·Q^T : lane holds S[s=32si+(r&3)+8(r>>2)+4hi1][t=ml5] ----
    f32x16 s0 = Z16, s1 = Z16;
    __builtin_amdgcn_s_setprio(1);
#pragma unroll
    for (int kd = 0; kd < 4; ++kd) {
      int koff = kd * 32 + hi1 * 16;
      bf16x8 a0 = *(const bf16x8*)(Ks + ml5 * 128 + (koff ^ swz));
      bf16x8 a1 = *(const bf16x8*)(Ks + (32 + ml5) * 128 + (koff ^ swz));
      s0 = __builtin_amdgcn_mfma_f32_32x32x16_bf16(a0, bq[kd], s0, 0, 0, 0);
      s1 = __builtin_amdgcn_mfma_f32_32x32x16_bf16(a1, bq[kd], s1, 0, 0, 0);
    }
    __builtin_amdgcn_s_setprio(0);
    if (msk && st == s) {
#pragma unroll
      for (int r = 0; r < 16; ++r) {
        int sl = st * 64 + (r & 3) + 8 * (r >> 2) + 4 * hi1;
        if (sl > t_glob) s0[r] = -1e30f;
        if (sl + 32 > t_glob) s1[r] = -1e30f;
      }
    }
    // ---- in-register online softmax with defer-max (T13) ----
    float t8[8];
#pragma unroll
    for (int r = 0; r < 8; ++r)
      t8[r] = fmaxf(fmaxf(s0[r], s0[r + 8]), fmaxf(s1[r], s1[r + 8]));
    float tm = fmaxf(fmaxf(fmaxf(t8[0], t8[1]), fmaxf(t8[2], t8[3])),
                     fmaxf(fmaxf(t8[4], t8[5]), fmaxf(t8[6], t8[7])));
    tm = fmaxf(tm, __shfl_xor(tm, 32));
    if (!__all(tm <= m_run + 8.0f)) {
      float m_new = fmaxf(m_run, tm);
      float sc2 = exp2f((m_run - m_new) * CE);
      l_run *= sc2;
#pragma unroll
      for (int r = 0; r < 16; ++r) { o0[r] *= sc2; o1[r] *= sc2; }
      m_run = m_new;
    }
    float mC = m_run * CE;
#pragma unroll
    for (int r = 0; r < 16; ++r) {
      s0[r] = exp2f(fmaf(s0[r], CE, -mC));
      s1[r] = exp2f(fmaf(s1[r], CE, -mC));
    }
    float a8[8];
#pragma unroll
    for (int r = 0; r < 8; ++r)
      a8[r] = (s0[r] + s0[r + 8]) + (s1[r] + s1[r + 8]);
    float ps = ((a8[0] + a8[1]) + (a8[2] + a8[3])) + ((a8[4] + a8[5]) + (a8[6] + a8[7]));
    ps += __shfl_xor(ps, 32);
    l_run += ps;
    // ---- pack P to bf16, redistribute across the 32-lane halves ----
    unsigned cc0[4][2], cc1[4][2];
#pragma unroll
    for (int q = 0; q < 4; ++q) {
      cc0[q][0] = packbf(s0[4 * q + 0], s0[4 * q + 1]);
      cc0[q][1] = packbf(s0[4 * q + 2], s0[4 * q + 3]);
      cc1[q][0] = packbf(s1[4 * q + 0], s1[4 * q + 1]);
      cc1[q][1] = packbf(s1[4 * q + 2], s1[4 * q + 3]);
    }
#define CCa(a, p) ((a) < 4 ? cc0[(a) & 3][p] : cc1[(a) & 3][p])
    union U4 { unsigned u[4]; bf16x8 v; };
    bf16x8 pb[4];
#pragma unroll
    for (int kb = 0; kb < 4; ++kb) {
      U4 t;
#pragma unroll
      for (int p = 0; p < 2; ++p) {
        unsigned x = CCa(2 * kb, p), y = CCa(2 * kb + 1, p);
        unsigned v = hi1 ? x : y;
        unsigned wv = hi1 ? y : x;
        unsigned vs = __shfl_xor(v, 32);
        t.u[p]     = hi1 ? vs : wv;
        t.u[2 + p] = hi1 ? wv : vs;
      }
      pb[kb] = t.v;
    }
#undef CCa
    // ---- O^T += V^T · P^T : lane holds O^T[d][t=ml5] ----
    __builtin_amdgcn_s_setprio(1);
#pragma unroll
    for (int kb = 0; kb < 4; ++kb) {
      int koff = kb * 32 + hi1 * 16;
      bf16x8 v0 = *(const bf16x8*)(Vs + ml5 * 128 + (koff ^ swz));
      bf16x8 v1 = *(const bf16x8*)(Vs + (32 + ml5) * 128 + (koff ^ swz));
      o0 = __builtin_amdgcn_mfma_f32_32x32x16_bf16(v0, pb[kb], o0, 0, 0, 0);
      o1 = __builtin_amdgcn_mfma_f32_32x32x16_bf16(v1, pb[kb], o1, 0, 0, 0);
    }
    __builtin_amdgcn_s_setprio(0);
    SCHEDB; LGKM0; SBAR;
    cur ^= 1;
  }
  // ---- epilogue: O /= l, store bf16 row t_glob ----
  float rl = 1.0f / l_run;
  int b = bh >> 4, h = bh & 15;
  unsigned short* orow = Op + (size_t)(t_glob * 8 + b) * 1024 + h * 64;
#pragma unroll
  for (int q2 = 0; q2 < 4; ++q2) {
    uint2 pk0, pk1;
    pk0.x = packbf(o0[4 * q2 + 0] * rl, o0[4 * q2 + 1] * rl);
    pk0.y = packbf(o0[4 * q2 + 2] * rl, o0[4 * q2 + 3] * rl);
    *(uint2*)(orow + 4 * hi1 + 8 * q2) = pk0;
    pk1.x = packbf(o1[4 * q2 + 0] * rl, o1[4 * q2 + 1] * rl);
    pk1.y = packbf(o1[4 * q2 + 2] * rl, o1[4 * q2 + 3] * rl);
    *(uint2*)(orow + 32 + 4 * hi1 + 8 * q2) = pk1;
  }
}

extern "C" void kernel_launch(void* const* d_in, const int* in_sizes, int n_in,
                              void* d_out, int out_size, void* d_ws, size_t ws_size,
                              hipStream_t stream) {
  const float* X  = (const float*)d_in[0];
  const float* KY = (const float*)d_in[1];
  const float* VY = (const float*)d_in[2];
  const float* Wq = (const float*)d_in[3];
  const float* bq = (const float*)d_in[4];
  const float* Wk = (const float*)d_in[5];
  const float* bk = (const float*)d_in[6];
  const float* Wv = (const float*)d_in[7];
  const float* bv = (const float*)d_in[8];
  const float* Wo = (const float*)d_in[9];
  const float* bo = (const float*)d_in[10];
  const int* mask = (const int*)d_in[11];
  char* ws = (char*)d_ws;
  unsigned short* XB  = (unsigned short*)(ws);                       // [3][8192][1024] bf16
  unsigned short* WT  = (unsigned short*)(ws + 48ll * 1024 * 1024);  // [3][1024][1024] bf16
  unsigned short* WOB = (unsigned short*)(ws + 54ll * 1024 * 1024);  // [1024][1024] bf16
  unsigned short* QP  = (unsigned short*)(ws + 56ll * 1024 * 1024);  // Q,K:[B,H,T,64]; V:[B,H,64,T]
  unsigned short* OP  = (unsigned short*)(ws + 104ll * 1024 * 1024); // [8192][1024] bf16

  prep<<<2816, 256, 0, stream>>>(X, KY, VY, Wo, Wq, Wk, Wv, XB, WOB, WT);
  gemm_qkv<<<dim3(64, 8, 3), 256, 0, stream>>>(XB, WT, bq, bk, bv, QP);
  attn_k<<<2048, 128, 0, stream>>>(QP, QP + 8388608, QP + 16777216, OP, mask);
  gemm_out<<<dim3(64, 8, 1), 256, 0, stream>>>(OP, WOB, bo, (float*)d_out);
}